// Round 4
// baseline (484.635 us; speedup 1.0000x reference)
//
#include <hip/hip_runtime.h>

#define H 2048

// inter-phase scratch (device globals; fully rewritten every call before read)
__device__ __align__(16) float g_p1[4 * H];   // layer-1 recurrent partial + both biases
__device__ __align__(16) float g_h0[H];       // layer-0 new h
__device__ __align__(16) float g_h1[H];       // layer-1 new h
__device__ __align__(16) float g_hid[13 * 64];// head hidden activations

// hand-rolled grid barrier state. Monotonic g_sense survives graph replays:
// each launch leaves g_count==0 and g_sense advanced by 3.
__device__ unsigned g_count = 0;
__device__ unsigned g_sense = 0;

__device__ const int c_HO[13]  = {5,1,1,1,1,1,1,1,9,1,3,1,1};
__device__ const int c_OFF[13] = {0,5,6,7,8,9,10,11,12,21,22,25,26};

__device__ __forceinline__ float sg(float x) { return 1.f / (1.f + __expf(-x)); }

__device__ __forceinline__ float wred(float x) {
    #pragma unroll
    for (int o = 32; o > 0; o >>= 1) x += __shfl_down(x, o);
    return x;
}

// proven pattern from the 250us pipeline: 8 global float4 loads issued
// back-to-back (8 KB/wave in flight), then fma against LDS vec. ~40 VGPRs.
__device__ __forceinline__ float dotrow(const float* __restrict__ row,
                                        const float* __restrict__ vecLDS, int lane) {
    float4 a[8];
    #pragma unroll
    for (int i = 0; i < 8; i++)
        a[i] = *reinterpret_cast<const float4*>(row + i * 256 + lane * 4);
    float acc = 0.f;
    #pragma unroll
    for (int i = 0; i < 8; i++) {
        float4 v = *reinterpret_cast<const float4*>(vecLDS + i * 256 + lane * 4);
        acc = fmaf(a[i].x, v.x, acc); acc = fmaf(a[i].y, v.y, acc);
        acc = fmaf(a[i].z, v.z, acc); acc = fmaf(a[i].w, v.w, acc);
    }
    return acc;
}

// sense-reversing centralized barrier, agent scope. Release: every arriving
// block's thread0 issues __threadfence() (L2 writeback on its XCD) BEFORE the
// arrive-add; acquire: __threadfence() (cache invalidate) after the sense flips,
// before any post-barrier data read. g_sense read via fetch_add(0) (RMW => fresh).
__device__ __forceinline__ void gridbar() {
    __syncthreads();
    if (threadIdx.x == 0) {
        __threadfence();  // release this block's writes device-wide
        unsigned my  = __hip_atomic_fetch_add(&g_sense, 0u, __ATOMIC_RELAXED,
                                              __HIP_MEMORY_SCOPE_AGENT);
        unsigned arr = __hip_atomic_fetch_add(&g_count, 1u, __ATOMIC_ACQ_REL,
                                              __HIP_MEMORY_SCOPE_AGENT);
        if (arr == gridDim.x - 1u) {
            __hip_atomic_store(&g_count, 0u, __ATOMIC_RELAXED, __HIP_MEMORY_SCOPE_AGENT);
            __hip_atomic_fetch_add(&g_sense, 1u, __ATOMIC_RELEASE, __HIP_MEMORY_SCOPE_AGENT);
        } else {
            while (__hip_atomic_load(&g_sense, __ATOMIC_RELAXED,
                                     __HIP_MEMORY_SCOPE_AGENT) == my)
                __builtin_amdgcn_s_sleep(1);
        }
        __threadfence();  // acquire: invalidate stale L1/L2 lines
    }
    __syncthreads();
}

__global__ __launch_bounds__(256) void fused(
    const float* __restrict__ lap, const int* __restrict__ idx,
    const float* __restrict__ h_s, const float* __restrict__ c_s,
    const float* __restrict__ e_team, const float* __restrict__ e_trk,
    const float* __restrict__ e_drv, const float* __restrict__ e_cmp,
    const float* __restrict__ Wih0, const float* __restrict__ Whh0,
    const float* __restrict__ bih0, const float* __restrict__ bhh0,
    const float* __restrict__ Wih1, const float* __restrict__ Whh1,
    const float* __restrict__ bih1, const float* __restrict__ bhh1,
    const float* __restrict__ ln_g, const float* __restrict__ ln_b,
    const float* __restrict__ W1, const float* __restrict__ b1,
    const float* __restrict__ W2, const float* __restrict__ b2,
    float* __restrict__ out)
{
    __shared__ float vec[2 * H];   // phase A: [0:H)=h_s[0], [H:2H)=h_s[1]; B: [0:H)=g_h0; C: ln(h1)
    __shared__ float xsh[96];
    __shared__ float gsh[4];
    __shared__ float red[8];
    __shared__ float mvs[2];

    int tid = threadIdx.x, w = tid >> 6, lane = tid & 63;
    int nb = gridDim.x;

    // ---- stage h_prev for BOTH layers (16 KB) + the 92-wide input x ----
    {
        float4* v4 = reinterpret_cast<float4*>(vec);
        const float4* s4 = reinterpret_cast<const float4*>(h_s);
        #pragma unroll
        for (int i = 0; i < 4; i++) v4[tid + i * 256] = s4[tid + i * 256];
        if (tid < 92) {
            float v;
            if (tid < 60)      v = lap[tid];
            else if (tid < 68) v = e_team[idx[3] * 8 + tid - 60];
            else if (tid < 76) v = e_trk [idx[2] * 8 + tid - 68];
            else if (tid < 84) v = e_drv [idx[1] * 8 + tid - 76];
            else               v = e_cmp [idx[0] * 8 + tid - 84];
            xsh[tid] = v;
        }
    }
    __syncthreads();

    // ---- Phase A: block-units 0..2047 = layer-0 cells (wave w = gate row),
    //      2048..4095 = Whh1 recurrent partial quads (1 row/wave) ----
    for (int bu = blockIdx.x; bu < 4096; bu += nb) {
        if (bu < 2048) {
            int j = bu;
            long row = j + (long)w * H;
            float acc = dotrow(Whh0 + row * H, vec, lane);
            const float* wr = Wih0 + row * 92;         // 92-wide input dot
            float p = xsh[lane] * wr[lane];
            if (lane < 28) p = fmaf(xsh[lane + 64], wr[lane + 64], p);
            acc = wred(acc + p);
            if (lane == 0) gsh[w] = acc + bih0[row] + bhh0[row];
            __syncthreads();
            if (tid == 0) {
                float gi = gsh[0], gf = gsh[1], gg = gsh[2], go = gsh[3];
                float cp = c_s[j];
                float cn = sg(gf) * cp + sg(gi) * tanhf(gg);
                float hn = sg(go) * tanhf(cn);
                out[j]         = hn;   // new_h[0]
                out[2 * H + j] = cn;   // new_c[0]
                g_h0[j] = hn;
            }
            __syncthreads();           // gsh reused next iteration
        } else {
            int r = (bu - 2048) * 4 + w;
            float acc = dotrow(Whh1 + (long)r * H, vec + H, lane);
            acc = wred(acc);
            if (lane == 0) g_p1[r] = acc + bih1[r] + bhh1[r];
        }
    }
    gridbar();

    // ---- Phase B: layer-1 cells (Wih1 @ h0_new + g_p1) ----
    {
        float4* v4 = reinterpret_cast<float4*>(vec);
        const float4* s4 = reinterpret_cast<const float4*>(g_h0);
        #pragma unroll
        for (int i = 0; i < 2; i++) v4[tid + i * 256] = s4[tid + i * 256];
    }
    __syncthreads();
    for (int j = blockIdx.x; j < 2048; j += nb) {
        long row = j + (long)w * H;
        float acc = dotrow(Wih1 + row * H, vec, lane);
        acc = wred(acc);
        if (lane == 0) gsh[w] = acc + g_p1[row];
        __syncthreads();
        if (tid == 0) {
            float gi = gsh[0], gf = gsh[1], gg = gsh[2], go = gsh[3];
            float cp = c_s[H + j];
            float cn = sg(gf) * cp + sg(gi) * tanhf(gg);
            float hn = sg(go) * tanhf(cn);
            out[H + j]     = hn;   // new_h[1]
            out[3 * H + j] = cn;   // new_c[1]
            g_h1[j] = hn;
        }
        __syncthreads();
    }
    gridbar();

    // ---- Phase C: LayerNorm (once per participating block) + head hidden ----
    {
        bool didLN = false;
        for (int bu = blockIdx.x; bu < 208; bu += nb) {
            if (!didLN) {
                didLN = true;
                const float4* s4 = reinterpret_cast<const float4*>(g_h1);
                float4 h0v = s4[tid], h1v = s4[tid + 256];
                float s  = h0v.x + h0v.y + h0v.z + h0v.w + h1v.x + h1v.y + h1v.z + h1v.w;
                float s2 = h0v.x*h0v.x + h0v.y*h0v.y + h0v.z*h0v.z + h0v.w*h0v.w
                         + h1v.x*h1v.x + h1v.y*h1v.y + h1v.z*h1v.z + h1v.w*h1v.w;
                s = wred(s); s2 = wred(s2);
                if (lane == 0) { red[w] = s; red[4 + w] = s2; }
                __syncthreads();
                if (tid == 0) {
                    float ts = red[0] + red[1] + red[2] + red[3];
                    float t2 = red[4] + red[5] + red[6] + red[7];
                    float mu = ts / (float)H;
                    float var = t2 / (float)H - mu * mu;
                    mvs[0] = mu; mvs[1] = rsqrtf(var + 1e-5f);
                }
                __syncthreads();
                float mu = mvs[0], rs = mvs[1];
                const float4* g4 = reinterpret_cast<const float4*>(ln_g);
                const float4* b4 = reinterpret_cast<const float4*>(ln_b);
                float4 ga = g4[tid], gb = g4[tid + 256];
                float4 ba = b4[tid], bb = b4[tid + 256];
                float4 o0, o1;
                o0.x = (h0v.x - mu) * rs * ga.x + ba.x;  o0.y = (h0v.y - mu) * rs * ga.y + ba.y;
                o0.z = (h0v.z - mu) * rs * ga.z + ba.z;  o0.w = (h0v.w - mu) * rs * ga.w + ba.w;
                o1.x = (h1v.x - mu) * rs * gb.x + bb.x;  o1.y = (h1v.y - mu) * rs * gb.y + bb.y;
                o1.z = (h1v.z - mu) * rs * gb.z + bb.z;  o1.w = (h1v.w - mu) * rs * gb.w + bb.w;
                float4* v4 = reinterpret_cast<float4*>(vec);
                v4[tid] = o0; v4[tid + 256] = o1;
                __syncthreads();
            }
            int k = bu >> 4;
            int o = (bu & 15) * 4 + w;                 // 1 hidden unit / wave
            float a = dotrow(W1 + ((long)k * 64 + o) * H, vec, lane);
            a = wred(a);
            if (lane == 0) {
                float t = a + b1[k * 64 + o];
                g_hid[k * 64 + o] = t > 0.f ? t : 0.f;
            }
        }
    }
    gridbar();

    // ---- Phase D: head output layer (117 tiny dots, one per wave) ----
    for (int r = blockIdx.x * 4 + w; r < 117; r += nb * 4) {
        int k = r / 9, p = r - k * 9;
        if (p < c_HO[k]) {
            float wv = W2[((long)(k * 9 + p)) * 64 + lane];
            float hh = g_hid[k * 64 + lane];
            float a = wred(wv * hh);
            if (lane == 0) out[4 * H + c_OFF[k] + p] = a + b2[k * 9 + p];
        }
    }
}

extern "C" void kernel_launch(void* const* d_in, const int* in_sizes, int n_in,
                              void* d_out, int out_size, void* d_ws, size_t ws_size,
                              hipStream_t stream) {
    // grid sized from the occupancy API (co-residency required by the barrier);
    // all phases are grid-stride so any grid size is correct.
    static int grid = 0;
    if (grid == 0) {
        int nb = 0;
        if (hipOccupancyMaxActiveBlocksPerMultiprocessor(&nb, fused, 256, 0) != hipSuccess || nb <= 0)
            nb = 2;
        if (nb > 8) nb = 8;                 // 32 waves/CU hardware cap
        long g = (long)nb * 256;            // 256 CUs on MI355X
        if (g > 2048) g = 2048;
        grid = (int)g;
    }

    void* in22[22];
    for (int i = 0; i < 22; i++) in22[i] = d_in[i];
    void* outp = d_out;
    void* args[23];
    for (int i = 0; i < 22; i++) args[i] = &in22[i];
    args[22] = &outp;

    if (hipLaunchCooperativeKernel(fused, dim3(grid), dim3(256), args, 0, stream)
            != hipSuccess && grid > 512) {
        grid = 512;  // conservative retry: 2 blocks/CU always fits this kernel
        hipLaunchCooperativeKernel(fused, dim3(grid), dim3(256), args, 0, stream);
    }
}

// Round 8
// 411.693 us; speedup vs baseline: 1.1772x; 1.1772x over previous
//
#include <hip/hip_runtime.h>

#define H 2048

// inter-phase scratch (device globals; fully rewritten every call before read)
__device__ __align__(16) float g_p1[4 * H];   // layer-1 recurrent partial + both biases
__device__ __align__(16) float g_h0[H];       // layer-0 new h
__device__ __align__(16) float g_h1[H];       // layer-1 new h
__device__ __align__(16) float g_hid[13 * 64];// head hidden activations

// hierarchical grid barrier state. 32 blocks/group -> up to 64 groups (grid<=2048).
// Each counter/sense lives on its own 128B line. Senses are monotonic, so state
// survives graph replays (counts return to 0, senses only advance).
__device__ __align__(128) unsigned g_gcnt[64 * 32];
__device__ __align__(128) unsigned g_gsen[64 * 32];
__device__ __align__(128) unsigned g_rcnt[32];
__device__ __align__(128) unsigned g_rsen[32];

__device__ const int c_HO[13]  = {5,1,1,1,1,1,1,1,9,1,3,1,1};
__device__ const int c_OFF[13] = {0,5,6,7,8,9,10,11,12,21,22,25,26};

__device__ __forceinline__ float sg(float x) { return 1.f / (1.f + __expf(-x)); }

__device__ __forceinline__ float wred(float x) {
    #pragma unroll
    for (int o = 32; o > 0; o >>= 1) x += __shfl_down(x, o);
    return x;
}

// proven pattern from the 250us pipeline: 8 global float4 loads issued
// back-to-back (8 KB/wave in flight), then fma against LDS vec. ~40 VGPRs.
__device__ __forceinline__ float dotrow(const float* __restrict__ row,
                                        const float* __restrict__ vecLDS, int lane) {
    float4 a[8];
    #pragma unroll
    for (int i = 0; i < 8; i++)
        a[i] = *reinterpret_cast<const float4*>(row + i * 256 + lane * 4);
    float acc = 0.f;
    #pragma unroll
    for (int i = 0; i < 8; i++) {
        float4 v = *reinterpret_cast<const float4*>(vecLDS + i * 256 + lane * 4);
        acc = fmaf(a[i].x, v.x, acc); acc = fmaf(a[i].y, v.y, acc);
        acc = fmaf(a[i].z, v.z, acc); acc = fmaf(a[i].w, v.w, acc);
    }
    return acc;
}

// two-level sense-reversing barrier. Max same-line serialization: 32 (group)
// + nGroups (root, <=64) atomics instead of gridDim arrivals on ONE line.
// grid must be a multiple of 32 (launcher guarantees: grid = k*256).
__device__ __forceinline__ void gridbar() {
    __syncthreads();
    if (threadIdx.x == 0) {
        __threadfence();   // release this block's global writes
        int gid = blockIdx.x >> 5;
        unsigned* gc = &g_gcnt[gid * 32];
        unsigned* gs = &g_gsen[gid * 32];
        unsigned mys = __hip_atomic_load(gs, __ATOMIC_RELAXED, __HIP_MEMORY_SCOPE_AGENT);
        unsigned a = __hip_atomic_fetch_add(gc, 1u, __ATOMIC_ACQ_REL, __HIP_MEMORY_SCOPE_AGENT);
        if (a == 31u) {                      // group leader -> root
            unsigned nG  = gridDim.x >> 5;
            unsigned myr = __hip_atomic_load(&g_rsen[0], __ATOMIC_RELAXED, __HIP_MEMORY_SCOPE_AGENT);
            unsigned b   = __hip_atomic_fetch_add(&g_rcnt[0], 1u, __ATOMIC_ACQ_REL, __HIP_MEMORY_SCOPE_AGENT);
            if (b == nG - 1u) {
                __hip_atomic_store(&g_rcnt[0], 0u, __ATOMIC_RELAXED, __HIP_MEMORY_SCOPE_AGENT);
                __hip_atomic_fetch_add(&g_rsen[0], 1u, __ATOMIC_RELEASE, __HIP_MEMORY_SCOPE_AGENT);
            } else {
                while (__hip_atomic_load(&g_rsen[0], __ATOMIC_RELAXED, __HIP_MEMORY_SCOPE_AGENT) == myr)
                    __builtin_amdgcn_s_sleep(2);
            }
            __hip_atomic_store(gc, 0u, __ATOMIC_RELAXED, __HIP_MEMORY_SCOPE_AGENT);
            __hip_atomic_fetch_add(gs, 1u, __ATOMIC_RELEASE, __HIP_MEMORY_SCOPE_AGENT);
        } else {
            while (__hip_atomic_load(gs, __ATOMIC_RELAXED, __HIP_MEMORY_SCOPE_AGENT) == mys)
                __builtin_amdgcn_s_sleep(2);
        }
        __threadfence();   // acquire: make all other blocks' writes visible
    }
    __syncthreads();
}

__global__ __launch_bounds__(256) void fused(
    const float* __restrict__ lap, const int* __restrict__ idx,
    const float* __restrict__ h_s, const float* __restrict__ c_s,
    const float* __restrict__ e_team, const float* __restrict__ e_trk,
    const float* __restrict__ e_drv, const float* __restrict__ e_cmp,
    const float* __restrict__ Wih0, const float* __restrict__ Whh0,
    const float* __restrict__ bih0, const float* __restrict__ bhh0,
    const float* __restrict__ Wih1, const float* __restrict__ Whh1,
    const float* __restrict__ bih1, const float* __restrict__ bhh1,
    const float* __restrict__ ln_g, const float* __restrict__ ln_b,
    const float* __restrict__ W1, const float* __restrict__ b1,
    const float* __restrict__ W2, const float* __restrict__ b2,
    float* __restrict__ out)
{
    __shared__ float vec[2 * H];   // phase A: [0:H)=h_s[0], [H:2H)=h_s[1]; B: [0:H)=g_h0; C: ln(h1)
    __shared__ float xsh[96];
    __shared__ float gsh[4];
    __shared__ float red[8];
    __shared__ float mvs[2];

    int tid = threadIdx.x, w = tid >> 6, lane = tid & 63;
    int nb = gridDim.x;

    // ---- stage h_prev for BOTH layers (16 KB) + the 92-wide input x ----
    {
        float4* v4 = reinterpret_cast<float4*>(vec);
        const float4* s4 = reinterpret_cast<const float4*>(h_s);
        #pragma unroll
        for (int i = 0; i < 4; i++) v4[tid + i * 256] = s4[tid + i * 256];
        if (tid < 92) {
            float v;
            if (tid < 60)      v = lap[tid];
            else if (tid < 68) v = e_team[idx[3] * 8 + tid - 60];
            else if (tid < 76) v = e_trk [idx[2] * 8 + tid - 68];
            else if (tid < 84) v = e_drv [idx[1] * 8 + tid - 76];
            else               v = e_cmp [idx[0] * 8 + tid - 84];
            xsh[tid] = v;
        }
    }
    __syncthreads();

    // ---- Phase A: block-units 0..2047 = layer-0 cells (wave w = gate row),
    //      2048..4095 = Whh1 recurrent partial quads (1 row/wave) ----
    for (int bu = blockIdx.x; bu < 4096; bu += nb) {
        if (bu < 2048) {
            int j = bu;
            long row = j + (long)w * H;
            float acc = dotrow(Whh0 + row * H, vec, lane);
            const float* wr = Wih0 + row * 92;         // 92-wide input dot
            float p = xsh[lane] * wr[lane];
            if (lane < 28) p = fmaf(xsh[lane + 64], wr[lane + 64], p);
            acc = wred(acc + p);
            if (lane == 0) gsh[w] = acc + bih0[row] + bhh0[row];
            __syncthreads();
            if (tid == 0) {
                float gi = gsh[0], gf = gsh[1], gg = gsh[2], go = gsh[3];
                float cp = c_s[j];
                float cn = sg(gf) * cp + sg(gi) * tanhf(gg);
                float hn = sg(go) * tanhf(cn);
                out[j]         = hn;   // new_h[0]
                out[2 * H + j] = cn;   // new_c[0]
                g_h0[j] = hn;
            }
            __syncthreads();           // gsh reused next iteration
        } else {
            int r = (bu - 2048) * 4 + w;
            float acc = dotrow(Whh1 + (long)r * H, vec + H, lane);
            acc = wred(acc);
            if (lane == 0) g_p1[r] = acc + bih1[r] + bhh1[r];
        }
    }
    gridbar();

    // ---- Phase B: layer-1 cells (Wih1 @ h0_new + g_p1) ----
    {
        float4* v4 = reinterpret_cast<float4*>(vec);
        const float4* s4 = reinterpret_cast<const float4*>(g_h0);
        #pragma unroll
        for (int i = 0; i < 2; i++) v4[tid + i * 256] = s4[tid + i * 256];
    }
    __syncthreads();
    for (int j = blockIdx.x; j < 2048; j += nb) {
        long row = j + (long)w * H;
        float acc = dotrow(Wih1 + row * H, vec, lane);
        acc = wred(acc);
        if (lane == 0) gsh[w] = acc + g_p1[row];
        __syncthreads();
        if (tid == 0) {
            float gi = gsh[0], gf = gsh[1], gg = gsh[2], go = gsh[3];
            float cp = c_s[H + j];
            float cn = sg(gf) * cp + sg(gi) * tanhf(gg);
            float hn = sg(go) * tanhf(cn);
            out[H + j]     = hn;   // new_h[1]
            out[3 * H + j] = cn;   // new_c[1]
            g_h1[j] = hn;
        }
        __syncthreads();
    }
    gridbar();

    // ---- Phase C: LayerNorm (once per participating block) + head hidden ----
    {
        bool didLN = false;
        for (int bu = blockIdx.x; bu < 208; bu += nb) {
            if (!didLN) {
                didLN = true;
                const float4* s4 = reinterpret_cast<const float4*>(g_h1);
                float4 h0v = s4[tid], h1v = s4[tid + 256];
                float s  = h0v.x + h0v.y + h0v.z + h0v.w + h1v.x + h1v.y + h1v.z + h1v.w;
                float s2 = h0v.x*h0v.x + h0v.y*h0v.y + h0v.z*h0v.z + h0v.w*h0v.w
                         + h1v.x*h1v.x + h1v.y*h1v.y + h1v.z*h1v.z + h1v.w*h1v.w;
                s = wred(s); s2 = wred(s2);
                if (lane == 0) { red[w] = s; red[4 + w] = s2; }
                __syncthreads();
                if (tid == 0) {
                    float ts = red[0] + red[1] + red[2] + red[3];
                    float t2 = red[4] + red[5] + red[6] + red[7];
                    float mu = ts / (float)H;
                    float var = t2 / (float)H - mu * mu;
                    mvs[0] = mu; mvs[1] = rsqrtf(var + 1e-5f);
                }
                __syncthreads();
                float mu = mvs[0], rs = mvs[1];
                const float4* g4 = reinterpret_cast<const float4*>(ln_g);
                const float4* b4 = reinterpret_cast<const float4*>(ln_b);
                float4 ga = g4[tid], gb = g4[tid + 256];
                float4 ba = b4[tid], bb = b4[tid + 256];
                float4 o0, o1;
                o0.x = (h0v.x - mu) * rs * ga.x + ba.x;  o0.y = (h0v.y - mu) * rs * ga.y + ba.y;
                o0.z = (h0v.z - mu) * rs * ga.z + ba.z;  o0.w = (h0v.w - mu) * rs * ga.w + ba.w;
                o1.x = (h1v.x - mu) * rs * gb.x + bb.x;  o1.y = (h1v.y - mu) * rs * gb.y + bb.y;
                o1.z = (h1v.z - mu) * rs * gb.z + bb.z;  o1.w = (h1v.w - mu) * rs * gb.w + bb.w;
                float4* v4 = reinterpret_cast<float4*>(vec);
                v4[tid] = o0; v4[tid + 256] = o1;
                __syncthreads();
            }
            int k = bu >> 4;
            int o = (bu & 15) * 4 + w;                 // 1 hidden unit / wave
            float a = dotrow(W1 + ((long)k * 64 + o) * H, vec, lane);
            a = wred(a);
            if (lane == 0) {
                float t = a + b1[k * 64 + o];
                g_hid[k * 64 + o] = t > 0.f ? t : 0.f;
            }
        }
    }
    gridbar();

    // ---- Phase D: head output layer (117 tiny dots, one per wave) ----
    for (int r = blockIdx.x * 4 + w; r < 117; r += nb * 4) {
        int k = r / 9, p = r - k * 9;
        if (p < c_HO[k]) {
            float wv = W2[((long)(k * 9 + p)) * 64 + lane];
            float hh = g_hid[k * 64 + lane];
            float a = wred(wv * hh);
            if (lane == 0) out[4 * H + c_OFF[k] + p] = a + b2[k * 9 + p];
        }
    }
}

extern "C" void kernel_launch(void* const* d_in, const int* in_sizes, int n_in,
                              void* d_out, int out_size, void* d_ws, size_t ws_size,
                              hipStream_t stream) {
    // grid sized from the occupancy API (co-residency required by the barrier);
    // all phases are grid-stride so any grid size is correct. grid = k*256 is
    // always a multiple of 32 (barrier group size).
    static int grid = 0;
    if (grid == 0) {
        int nb = 0;
        if (hipOccupancyMaxActiveBlocksPerMultiprocessor(&nb, fused, 256, 0) != hipSuccess || nb <= 0)
            nb = 2;
        if (nb > 8) nb = 8;                 // 32 waves/CU hardware cap
        long g = (long)nb * 256;            // 256 CUs on MI355X
        if (g > 2048) g = 2048;
        grid = (int)g;
    }

    void* in22[22];
    for (int i = 0; i < 22; i++) in22[i] = d_in[i];
    void* outp = d_out;
    void* args[23];
    for (int i = 0; i < 22; i++) args[i] = &in22[i];
    args[22] = &outp;

    if (hipLaunchCooperativeKernel(fused, dim3(grid), dim3(256), args, 0, stream)
            != hipSuccess && grid > 512) {
        grid = 512;  // conservative retry: 2 blocks/CU always fits this kernel
        hipLaunchCooperativeKernel(fused, dim3(grid), dim3(256), args, 0, stream);
    }
}

// Round 20
// 307.009 us; speedup vs baseline: 1.5786x; 1.3410x over previous
//
#include <hip/hip_runtime.h>

#define H 2048

// inter-phase scratch (device globals; fully rewritten every call before read).
// ALL cross-barrier data goes through agent-scope relaxed atomics (coherence-point
// ops, no L2 writeback/invalidate) -- this is what lets the barrier be fence-free.
__device__ __align__(16) float g_p1[4 * H];   // layer-1 recurrent partial + both biases
__device__ __align__(16) float g_h0[H];       // layer-0 new h
__device__ __align__(16) float g_h1[H];       // layer-1 new h
__device__ __align__(16) float g_hid[13 * 64];// head hidden activations

// hierarchical grid barrier state. 32 blocks/group -> up to 64 groups (grid<=2048).
// Each counter/sense on its own 128B line. Senses monotonic => graph-replay safe.
__device__ __align__(128) unsigned g_gcnt[64 * 32];
__device__ __align__(128) unsigned g_gsen[64 * 32];
__device__ __align__(128) unsigned g_rcnt[32];
__device__ __align__(128) unsigned g_rsen[32];

__device__ const int c_HO[13]  = {5,1,1,1,1,1,1,1,9,1,3,1,1};
__device__ const int c_OFF[13] = {0,5,6,7,8,9,10,11,12,21,22,25,26};

__device__ __forceinline__ float sg(float x) { return 1.f / (1.f + __expf(-x)); }

__device__ __forceinline__ float wred(float x) {
    #pragma unroll
    for (int o = 32; o > 0; o >>= 1) x += __shfl_down(x, o);
    return x;
}

// coherent scalar access to the g_* scratch: agent-scope relaxed atomics.
// These compile to sc-flagged global ops that bypass the non-coherent L2s;
// no buffer_wbl2/buffer_inv cache maintenance is ever emitted.
__device__ __forceinline__ void cstore(float* p, float v) {
    __hip_atomic_store(p, v, __ATOMIC_RELAXED, __HIP_MEMORY_SCOPE_AGENT);
}
__device__ __forceinline__ float cload(const float* p) {
    return __hip_atomic_load(p, __ATOMIC_RELAXED, __HIP_MEMORY_SCOPE_AGENT);
}

// proven pattern from the 250us pipeline: 8 global float4 loads issued
// back-to-back (8 KB/wave in flight), then fma against LDS vec. ~40 VGPRs.
__device__ __forceinline__ float dotrow(const float* __restrict__ row,
                                        const float* __restrict__ vecLDS, int lane) {
    float4 a[8];
    #pragma unroll
    for (int i = 0; i < 8; i++)
        a[i] = *reinterpret_cast<const float4*>(row + i * 256 + lane * 4);
    float acc = 0.f;
    #pragma unroll
    for (int i = 0; i < 8; i++) {
        float4 v = *reinterpret_cast<const float4*>(vecLDS + i * 256 + lane * 4);
        acc = fmaf(a[i].x, v.x, acc); acc = fmaf(a[i].y, v.y, acc);
        acc = fmaf(a[i].z, v.z, acc); acc = fmaf(a[i].w, v.w, acc);
    }
    return acc;
}

// FENCE-FREE two-level sense-reversing barrier. No __threadfence anywhere:
// cross-barrier data moves via sc-flagged atomics (cstore/cload), and each
// thread drains its own vmem (s_waitcnt vmcnt(0)) before arrival -- for
// sc-flagged stores, vmcnt retirement == visibility at the coherence point.
// All barrier atomics RELAXED; intra-protocol ordering via explicit waitcnt.
// DIAGNOSTIC WATCHDOG: spin loops escape after 200k iterations (~50 ms).
// Legit barrier skew is <=~50 us (~200 iterations) -- 1000x margin, so the
// watchdog is inert when the protocol works. If the protocol were to hang,
// the kernel completes with wrong data => clean absmax failure instead of an
// ambiguous GPU-hang/core-dump. Converts deadlock into a diagnosable signal.
__device__ __forceinline__ void gridbar() {
    // every thread: its coherent stores must be globally visible before arrive
    asm volatile("s_waitcnt vmcnt(0)" ::: "memory");
    __syncthreads();
    if (threadIdx.x == 0) {
        int gid = blockIdx.x >> 5;
        unsigned* gc = &g_gcnt[gid * 32];
        unsigned* gs = &g_gsen[gid * 32];
        unsigned mys = __hip_atomic_load(gs, __ATOMIC_RELAXED, __HIP_MEMORY_SCOPE_AGENT);
        unsigned a = __hip_atomic_fetch_add(gc, 1u, __ATOMIC_RELAXED, __HIP_MEMORY_SCOPE_AGENT);
        if (a == 31u) {                      // group leader -> root
            unsigned nG  = gridDim.x >> 5;
            unsigned myr = __hip_atomic_load(&g_rsen[0], __ATOMIC_RELAXED, __HIP_MEMORY_SCOPE_AGENT);
            unsigned b   = __hip_atomic_fetch_add(&g_rcnt[0], 1u, __ATOMIC_RELAXED, __HIP_MEMORY_SCOPE_AGENT);
            if (b == nG - 1u) {
                __hip_atomic_store(&g_rcnt[0], 0u, __ATOMIC_RELAXED, __HIP_MEMORY_SCOPE_AGENT);
                asm volatile("s_waitcnt vmcnt(0)" ::: "memory");   // reset before release
                __hip_atomic_fetch_add(&g_rsen[0], 1u, __ATOMIC_RELAXED, __HIP_MEMORY_SCOPE_AGENT);
            } else {
                int sp = 0;
                while (__hip_atomic_load(&g_rsen[0], __ATOMIC_RELAXED, __HIP_MEMORY_SCOPE_AGENT) == myr) {
                    __builtin_amdgcn_s_sleep(2);
                    if (++sp > 200000) break;   // watchdog (inert when healthy)
                }
            }
            __hip_atomic_store(gc, 0u, __ATOMIC_RELAXED, __HIP_MEMORY_SCOPE_AGENT);
            asm volatile("s_waitcnt vmcnt(0)" ::: "memory");       // reset before release
            __hip_atomic_fetch_add(gs, 1u, __ATOMIC_RELAXED, __HIP_MEMORY_SCOPE_AGENT);
        } else {
            int sp = 0;
            while (__hip_atomic_load(gs, __ATOMIC_RELAXED, __HIP_MEMORY_SCOPE_AGENT) == mys) {
                __builtin_amdgcn_s_sleep(2);
                if (++sp > 200000) break;       // watchdog (inert when healthy)
            }
        }
        asm volatile("" ::: "memory");
    }
    __syncthreads();
}

__global__ __launch_bounds__(256) void fused(
    const float* __restrict__ lap, const int* __restrict__ idx,
    const float* __restrict__ h_s, const float* __restrict__ c_s,
    const float* __restrict__ e_team, const float* __restrict__ e_trk,
    const float* __restrict__ e_drv, const float* __restrict__ e_cmp,
    const float* __restrict__ Wih0, const float* __restrict__ Whh0,
    const float* __restrict__ bih0, const float* __restrict__ bhh0,
    const float* __restrict__ Wih1, const float* __restrict__ Whh1,
    const float* __restrict__ bih1, const float* __restrict__ bhh1,
    const float* __restrict__ ln_g, const float* __restrict__ ln_b,
    const float* __restrict__ W1, const float* __restrict__ b1,
    const float* __restrict__ W2, const float* __restrict__ b2,
    float* __restrict__ out)
{
    __shared__ float vec[2 * H];   // phase A: [0:H)=h_s[0], [H:2H)=h_s[1]; B: [0:H)=g_h0; C: ln(h1)
    __shared__ float xsh[96];
    __shared__ float gsh[4];
    __shared__ float red[8];
    __shared__ float mvs[2];

    int tid = threadIdx.x, w = tid >> 6, lane = tid & 63;
    int nb = gridDim.x;

    // ---- stage h_prev for BOTH layers (16 KB) + the 92-wide input x ----
    {
        float4* v4 = reinterpret_cast<float4*>(vec);
        const float4* s4 = reinterpret_cast<const float4*>(h_s);
        #pragma unroll
        for (int i = 0; i < 4; i++) v4[tid + i * 256] = s4[tid + i * 256];
        if (tid < 92) {
            float v;
            if (tid < 60)      v = lap[tid];
            else if (tid < 68) v = e_team[idx[3] * 8 + tid - 60];
            else if (tid < 76) v = e_trk [idx[2] * 8 + tid - 68];
            else if (tid < 84) v = e_drv [idx[1] * 8 + tid - 76];
            else               v = e_cmp [idx[0] * 8 + tid - 84];
            xsh[tid] = v;
        }
    }
    __syncthreads();

    // ---- Phase A: block-units 0..2047 = layer-0 cells (wave w = gate row),
    //      2048..4095 = Whh1 recurrent partial quads (1 row/wave) ----
    for (int bu = blockIdx.x; bu < 4096; bu += nb) {
        if (bu < 2048) {
            int j = bu;
            long row = j + (long)w * H;
            float acc = dotrow(Whh0 + row * H, vec, lane);
            const float* wr = Wih0 + row * 92;         // 92-wide input dot
            float p = xsh[lane] * wr[lane];
            if (lane < 28) p = fmaf(xsh[lane + 64], wr[lane + 64], p);
            acc = wred(acc + p);
            if (lane == 0) gsh[w] = acc + bih0[row] + bhh0[row];
            __syncthreads();
            if (tid == 0) {
                float gi = gsh[0], gf = gsh[1], gg = gsh[2], go = gsh[3];
                float cp = c_s[j];
                float cn = sg(gf) * cp + sg(gi) * tanhf(gg);
                float hn = sg(go) * tanhf(cn);
                out[j]         = hn;   // new_h[0]
                out[2 * H + j] = cn;   // new_c[0]
                cstore(&g_h0[j], hn);
            }
            __syncthreads();           // gsh reused next iteration
        } else {
            int r = (bu - 2048) * 4 + w;
            float acc = dotrow(Whh1 + (long)r * H, vec + H, lane);
            acc = wred(acc);
            if (lane == 0) cstore(&g_p1[r], acc + bih1[r] + bhh1[r]);
        }
    }
    gridbar();

    // ---- Phase B: layer-1 cells (Wih1 @ h0_new + g_p1) ----
    #pragma unroll
    for (int i = 0; i < 8; i++) vec[tid + i * 256] = cload(&g_h0[tid + i * 256]);
    __syncthreads();
    for (int j = blockIdx.x; j < 2048; j += nb) {
        long row = j + (long)w * H;
        float acc = dotrow(Wih1 + row * H, vec, lane);
        acc = wred(acc);
        if (lane == 0) gsh[w] = acc + cload(&g_p1[row]);
        __syncthreads();
        if (tid == 0) {
            float gi = gsh[0], gf = gsh[1], gg = gsh[2], go = gsh[3];
            float cp = c_s[H + j];
            float cn = sg(gf) * cp + sg(gi) * tanhf(gg);
            float hn = sg(go) * tanhf(cn);
            out[H + j]     = hn;   // new_h[1]
            out[3 * H + j] = cn;   // new_c[1]
            cstore(&g_h1[j], hn);
        }
        __syncthreads();
    }
    gridbar();

    // ---- Phase C: LayerNorm (once per participating block) + head hidden ----
    {
        bool didLN = false;
        for (int bu = blockIdx.x; bu < 208; bu += nb) {
            if (!didLN) {
                didLN = true;
                float hv[8];
                float s = 0.f, s2 = 0.f;
                #pragma unroll
                for (int i = 0; i < 8; i++) {
                    float x = cload(&g_h1[tid + i * 256]);
                    hv[i] = x; s += x; s2 = fmaf(x, x, s2);
                }
                s = wred(s); s2 = wred(s2);
                if (lane == 0) { red[w] = s; red[4 + w] = s2; }
                __syncthreads();
                if (tid == 0) {
                    float ts = red[0] + red[1] + red[2] + red[3];
                    float t2 = red[4] + red[5] + red[6] + red[7];
                    float mu = ts / (float)H;
                    float var = t2 / (float)H - mu * mu;
                    mvs[0] = mu; mvs[1] = rsqrtf(var + 1e-5f);
                }
                __syncthreads();
                float mu = mvs[0], rs = mvs[1];
                #pragma unroll
                for (int i = 0; i < 8; i++) {
                    int e = tid + i * 256;
                    vec[e] = (hv[i] - mu) * rs * ln_g[e] + ln_b[e];
                }
                __syncthreads();
            }
            int k = bu >> 4;
            int o = (bu & 15) * 4 + w;                 // 1 hidden unit / wave
            float a = dotrow(W1 + ((long)k * 64 + o) * H, vec, lane);
            a = wred(a);
            if (lane == 0) {
                float t = a + b1[k * 64 + o];
                cstore(&g_hid[k * 64 + o], t > 0.f ? t : 0.f);
            }
        }
    }
    gridbar();

    // ---- Phase D: head output layer (117 tiny dots, one per wave) ----
    for (int r = blockIdx.x * 4 + w; r < 117; r += nb * 4) {
        int k = r / 9, p = r - k * 9;
        if (p < c_HO[k]) {
            float wv = W2[((long)(k * 9 + p)) * 64 + lane];
            float hh = cload(&g_hid[k * 64 + lane]);
            float a = wred(wv * hh);
            if (lane == 0) out[4 * H + c_OFF[k] + p] = a + b2[k * 9 + p];
        }
    }
}

extern "C" void kernel_launch(void* const* d_in, const int* in_sizes, int n_in,
                              void* d_out, int out_size, void* d_ws, size_t ws_size,
                              hipStream_t stream) {
    // grid sized from the occupancy API (co-residency required by the barrier);
    // all phases are grid-stride so any grid size is correct. grid = k*256 is
    // always a multiple of 32 (barrier group size).
    static int grid = 0;
    if (grid == 0) {
        int nb = 0;
        if (hipOccupancyMaxActiveBlocksPerMultiprocessor(&nb, fused, 256, 0) != hipSuccess || nb <= 0)
            nb = 2;
        if (nb > 8) nb = 8;                 // 32 waves/CU hardware cap
        long g = (long)nb * 256;            // 256 CUs on MI355X
        if (g > 2048) g = 2048;
        grid = (int)g;
    }

    void* in22[22];
    for (int i = 0; i < 22; i++) in22[i] = d_in[i];
    void* outp = d_out;
    void* args[23];
    for (int i = 0; i < 22; i++) args[i] = &in22[i];
    args[22] = &outp;

    if (hipLaunchCooperativeKernel(fused, dim3(grid), dim3(256), args, 0, stream)
            != hipSuccess && grid > 512) {
        grid = 512;  // conservative retry: 2 blocks/CU always fits this kernel
        hipLaunchCooperativeKernel(fused, dim3(grid), dim3(256), args, 0, stream);
    }
}